// Round 1
// baseline (268.393 us; speedup 1.0000x reference)
//
#include <hip/hip_runtime.h>

// Problem constants (match reference)
#define HH 480
#define WW 640
#define HP 30
#define WP 40
#define NP (HP * WP)   // 1200 points per batch
#define BB 128

// One thread per sample point: computes grid output, bilinear-samples depth,
// scatter-adds into the dense sparse_depth image.
__global__ __launch_bounds__(256) void sample_scatter_kernel(
    const float* __restrict__ pooled,   // [B, 2, HP, WP]
    const float* __restrict__ depth,    // [B, 1, H, W]
    float* __restrict__ sparse,         // [B, 1, H, W] (pre-zeroed)
    float2* __restrict__ grid_out)      // [B, HP, WP, 2]
{
    int idx = blockIdx.x * blockDim.x + threadIdx.x;
    if (idx >= BB * NP) return;
    int b = idx / NP;
    int p = idx - b * NP;

    float gx = pooled[(size_t)b * 2 * NP + p];        // channel 0 = x
    float gy = pooled[(size_t)b * 2 * NP + NP + p];   // channel 1 = y

    // grid_to_sample (second output), reference arithmetic order
    float grid_w = (2.0f * gx - (float)WW) / (float)WW;
    float grid_h = (2.0f * gy - (float)HH) / (float)HH;
    grid_out[idx] = make_float2(grid_w, grid_h);

    // Bilinear sample with align_corners=True, zeros padding —
    // replicate the reference's round-trip arithmetic exactly.
    float x = (grid_w + 1.0f) * 0.5f * (float)(WW - 1);
    float y = (grid_h + 1.0f) * 0.5f * (float)(HH - 1);
    float x0f = floorf(x), y0f = floorf(y);
    float wx1 = x - x0f, wx0 = 1.0f - wx1;
    float wy1 = y - y0f, wy0 = 1.0f - wy1;
    int x0 = (int)x0f, y0 = (int)y0f;
    int x1 = x0 + 1,  y1 = y0 + 1;

    const float* img = depth + (size_t)b * HH * WW;

    float v00 = (y0 >= 0 && y0 <= HH - 1 && x0 >= 0 && x0 <= WW - 1) ? img[y0 * WW + x0] : 0.0f;
    float v01 = (y0 >= 0 && y0 <= HH - 1 && x1 >= 0 && x1 <= WW - 1) ? img[y0 * WW + x1] : 0.0f;
    float v10 = (y1 >= 0 && y1 <= HH - 1 && x0 >= 0 && x0 <= WW - 1) ? img[y1 * WW + x0] : 0.0f;
    float v11 = (y1 >= 0 && y1 <= HH - 1 && x1 >= 0 && x1 <= WW - 1) ? img[y1 * WW + x1] : 0.0f;

    float v = v00 * wy0 * wx0 + v01 * wy0 * wx1 + v10 * wy1 * wx0 + v11 * wy1 * wx1;

    // rows/cols: round (half-to-even, like jnp.round) THEN clip, like reference
    float ry = rintf(gy), rx = rintf(gx);
    int row = (int)fminf(fmaxf(ry, 0.0f), (float)(HH - 1));
    int col = (int)fminf(fmaxf(rx, 0.0f), (float)(WW - 1));

    atomicAdd(&sparse[(size_t)b * HH * WW + row * WW + col], v);
}

extern "C" void kernel_launch(void* const* d_in, const int* in_sizes, int n_in,
                              void* d_out, int out_size, void* d_ws, size_t ws_size,
                              hipStream_t stream) {
    const float* pooled = (const float*)d_in[0];   // [B,2,HP,WP] fp32
    const float* depth  = (const float*)d_in[1];   // [B,1,H,W]  fp32

    float* out = (float*)d_out;
    float* sparse = out;                               // first output: B*H*W floats
    float2* grid_out = (float2*)(out + (size_t)BB * HH * WW);  // second output: B*NP float2

    // d_out is poisoned to 0xAA before every timed launch — zero the dense image.
    hipMemsetAsync(sparse, 0, (size_t)BB * HH * WW * sizeof(float), stream);

    int n = BB * NP;
    sample_scatter_kernel<<<(n + 255) / 256, 256, 0, stream>>>(pooled, depth, sparse, grid_out);
}